// Round 8
// baseline (292.788 us; speedup 1.0000x reference)
//
#include <hip/hip_runtime.h>
#include <hip/hip_bf16.h>

// Kalman recurrence, exact chunked parallelization. Round 8.
//   x[k+1] = M x[k] + L y[:,k],  M = A - L H,  yhat[:,k] = H x[k], x[0]=0
// Chunk T=16:  yhat[cT+t] = F_t x_c + sum_{s<t} K_{t-1-s} y[cT+s]
//   F_t = H M^t, K_d = H M^d L, v_c = sum_t M^{15-t} L y[cT+t]
//   x_{c+1} = P x_c + v_c, P = M^16.  3-level fp32 scan over C=16384 chunks.
// Round-8: k_p1 was 85us = 13 sequential LDS-pipe-bound matmuls on one CU.
// (a) register-tiled mm128 (8x4 tile, 12 b128-reads / 128 FMA -> ~3.4x fewer
// LDS instrs); (b) k_p1 only builds M..M16 (6 matmuls); the M32..M2048 squaring
// chain (needed only by scanB) rides as an extra block inside k_mfma<0>.

#define NSTEP 262144
#define T 16
#define CCH (NSTEP / T)          // 16384 chunks
#define KDIM (64 + 32 * T)       // 576
#define MOUT (32 * T)            // 512
#define NBLK 128                 // scan blocks
#define SB (CCH / NBLK)          // 128 chunks per scan block

typedef _Float16 f16;
typedef _Float16 f16x4 __attribute__((ext_vector_type(4)));
typedef _Float16 f16x8 __attribute__((ext_vector_type(8)));
typedef float f32x4 __attribute__((ext_vector_type(4)));

// Fragment-major tile layout for a [rows][K] f16 matrix:
//   slot(ct, ks, lg, l) = ((ct*KS + ks)*4 + lg)*16 + l   (one slot = 8 f16 = 16B)
//   element (r, k): ct=r>>4, l=r&15, ks=k>>5, lg=(k>>3)&3, e=k&7

// ---- workspace layout (float units) ----
#define OFF_ZH 0                          // Zh tiled: CCH rows x 576 k (KS=18)
#define SZ_ZH  (CCH * KDIM / 2)
#define OFF_VT (OFF_ZH + SZ_ZH)           // VT: f32 [CCH][64]
#define SZ_VT  (CCH * 64)
#define OFF_MP (OFF_VT + SZ_VT)           // M powers: 0:M 1:M2 2:M4 3:M8 4:M16 5:M2048 6:M3 7:M12
#define SZ_MP  (8 * 4096)
#define OFF_BO (OFF_MP + SZ_MP)           // BOh tiled: 512 rows x 576 k (KS=18)
#define SZ_BO  (MOUT * KDIM / 2)
#define OFF_GC (OFF_BO + SZ_BO)           // GCh tiled: 64 rows x 512 k (KS=16)
#define SZ_GC  (64 * 512 / 2)
#define OFF_FB (OFF_GC + SZ_GC)           // Fbuf: f32 16 x (32x64)
#define SZ_FB  (16 * 2048)
#define OFF_GB (OFF_FB + SZ_FB)           // Gbuf: f32 16 x (64x32)
#define SZ_GB  (16 * 2048)
#define OFF_KD (OFF_GB + SZ_GB)           // Kd: f32 15 x (32x32)
#define SZ_KD  (15 * 1024)
#define OFF_W  (OFF_KD + SZ_KD)           // [128][64]
#define OFF_XB (OFF_W + NBLK * 64)        // [128][64]

// ---- register-tiled 64x64 LDS matmul, 128 threads, 8x4 tile per thread.
//      X,Y,D are LDS with row stride 68 (272B, 16B-aligned). gdst optional global.
__device__ __forceinline__ void mm128(const float* __restrict__ X,
                                      const float* __restrict__ Y,
                                      float* __restrict__ D,
                                      float* __restrict__ gdst,
                                      const int tid) {
  const int i0 = (tid >> 4) * 8, j0 = (tid & 15) * 4;
  float acc[8][4] = {};
  for (int k0 = 0; k0 < 64; k0 += 4) {
    float4 yc[4];
#pragma unroll
    for (int kk = 0; kk < 4; ++kk)
      yc[kk] = *reinterpret_cast<const float4*>(&Y[(k0 + kk) * 68 + j0]);
#pragma unroll
    for (int r = 0; r < 8; ++r) {
      const float4 xr = *reinterpret_cast<const float4*>(&X[(i0 + r) * 68 + k0]);
      const float xs[4] = {xr.x, xr.y, xr.z, xr.w};
#pragma unroll
      for (int kk = 0; kk < 4; ++kk) {
        acc[r][0] = fmaf(xs[kk], yc[kk].x, acc[r][0]);
        acc[r][1] = fmaf(xs[kk], yc[kk].y, acc[r][1]);
        acc[r][2] = fmaf(xs[kk], yc[kk].z, acc[r][2]);
        acc[r][3] = fmaf(xs[kk], yc[kk].w, acc[r][3]);
      }
    }
  }
#pragma unroll
  for (int r = 0; r < 8; ++r) {
    const float4 v = make_float4(acc[r][0], acc[r][1], acc[r][2], acc[r][3]);
    if (D) *reinterpret_cast<float4*>(&D[(i0 + r) * 68 + j0]) = v;
    if (gdst) *reinterpret_cast<float4*>(&gdst[(i0 + r) * 64 + j0]) = v;
  }
}

// ---- pack: Zh[c][64+t*32+i] = (f16) y[i][c*16+t], tiled layout, 16 chunks/block ----
__global__ __launch_bounds__(256) void k_pack(const float* __restrict__ y,
                                              f16* __restrict__ Zt) {
  __shared__ f16 Lt[32][264];               // [i][local timestep 0..255], +8 pad
  const int tid = threadIdx.x;
  const int ct = blockIdx.x;                // c-tile: chunks ct*16 .. ct*16+15
  const size_t colbase = (size_t)ct * 256;  // timestep base
#pragma unroll
  for (int v = 0; v < 8; ++v) {
    const int fidx = v * 256 + tid;         // 2048 float4 over [32][256]
    const int row = fidx >> 6, col4 = fidx & 63;
    const float4 w = *reinterpret_cast<const float4*>(y + (size_t)row * NSTEP + colbase + col4 * 4);
    f16x4 h = {(f16)w.x, (f16)w.y, (f16)w.z, (f16)w.w};
    *reinterpret_cast<f16x4*>(&Lt[row][col4 * 4]) = h;
  }
  __syncthreads();
#pragma unroll
  for (int v = 0; v < 4; ++v) {
    const int s = v * 256 + tid;            // slot within block: ((t*4)+lg)*16 + l
    const int l = s & 15, lg = (s >> 4) & 3, t = s >> 6;
    f16x8 hv;
#pragma unroll
    for (int e = 0; e < 8; ++e) hv[e] = Lt[lg * 8 + e][l * 16 + t];
    *reinterpret_cast<f16x8*>(Zt + ((size_t)(ct * 18 + 2 + t) * 64 + lg * 16 + l) * 8) = hv;
  }
}

// ---- P1: M = A - L H; powers M2,M3,M4,M8,M12,M16 (register-tiled, 128 thr);
//      seeds Fbuf[0]=H, Gbuf[0]=L.  M32..M2048 moved into k_mfma<0>. ----
__global__ __launch_bounds__(128) void k_p1(const float* __restrict__ A,
                                            const float* __restrict__ H,
                                            const float* __restrict__ L,
                                            float* __restrict__ MP,
                                            float* __restrict__ Fb,
                                            float* __restrict__ Gb) {
  __shared__ __align__(16) float S0[64 * 68], S1[64 * 68], S2[64 * 68];
  const int tid = threadIdx.x;
  // stage H -> S0 rows 0..31 (Hs[q][j]); L^T -> S1 rows 0..31 (LT[q][i])
  for (int e = tid; e < 512; e += 128) {
    const float4 v = reinterpret_cast<const float4*>(H)[e];
    const int q = e >> 4, j = (e & 15) << 2;
    *reinterpret_cast<float4*>(&S0[q * 68 + j]) = v;
  }
  for (int e = tid; e < 512; e += 128) {
    const float4 v = reinterpret_cast<const float4*>(L)[e];
    const int i = e >> 3, q = (e & 7) << 2;
    S1[(q + 0) * 68 + i] = v.x;
    S1[(q + 1) * 68 + i] = v.y;
    S1[(q + 2) * 68 + i] = v.z;
    S1[(q + 3) * 68 + i] = v.w;
  }
  for (int e = tid; e < 512; e += 128) {    // seed Fb = H, Gb = L
    reinterpret_cast<float4*>(Fb)[e] = reinterpret_cast<const float4*>(H)[e];
    reinterpret_cast<float4*>(Gb)[e] = reinterpret_cast<const float4*>(L)[e];
  }
  __syncthreads();
  // M = A - L H  (8x4 tile) -> S2 + MP slot 0
  {
    const int i0 = (tid >> 4) * 8, j0 = (tid & 15) * 4;
    float acc[8][4];
#pragma unroll
    for (int r = 0; r < 8; ++r) {
      const float4 a = *reinterpret_cast<const float4*>(&A[(i0 + r) * 64 + j0]);
      acc[r][0] = a.x; acc[r][1] = a.y; acc[r][2] = a.z; acc[r][3] = a.w;
    }
    for (int q = 0; q < 32; ++q) {
      const float4 hq = *reinterpret_cast<const float4*>(&S0[q * 68 + j0]);
      const float4 l0 = *reinterpret_cast<const float4*>(&S1[q * 68 + i0]);
      const float4 l1 = *reinterpret_cast<const float4*>(&S1[q * 68 + i0 + 4]);
      const float ls[8] = {l0.x, l0.y, l0.z, l0.w, l1.x, l1.y, l1.z, l1.w};
#pragma unroll
      for (int r = 0; r < 8; ++r) {
        acc[r][0] = fmaf(-ls[r], hq.x, acc[r][0]);
        acc[r][1] = fmaf(-ls[r], hq.y, acc[r][1]);
        acc[r][2] = fmaf(-ls[r], hq.z, acc[r][2]);
        acc[r][3] = fmaf(-ls[r], hq.w, acc[r][3]);
      }
    }
    __syncthreads();                        // Hs/LT reads done before S2 write? (S2 untouched; sync for S0/S1 reuse below)
#pragma unroll
    for (int r = 0; r < 8; ++r) {
      const float4 v = make_float4(acc[r][0], acc[r][1], acc[r][2], acc[r][3]);
      *reinterpret_cast<float4*>(&S2[(i0 + r) * 68 + j0]) = v;
      *reinterpret_cast<float4*>(&MP[(i0 + r) * 64 + j0]) = v;
    }
  }
  __syncthreads();
  // chain: M2=M*M, M3=M2*M, M4=M2^2, M8=M4^2, M12=M4*M8, M16=M8^2
  mm128(S2, S2, S0, MP + 1 * 4096, tid); __syncthreads();     // M2 -> S0
  mm128(S0, S2, nullptr, MP + 6 * 4096, tid); __syncthreads(); // M3 (global only)
  mm128(S0, S0, S1, MP + 2 * 4096, tid); __syncthreads();     // M4 -> S1
  mm128(S1, S1, S0, MP + 3 * 4096, tid); __syncthreads();     // M8 -> S0 (M2 dead)
  mm128(S1, S0, nullptr, MP + 7 * 4096, tid); __syncthreads(); // M12 (global only)
  mm128(S0, S0, nullptr, MP + 4 * 4096, tid);                  // M16 (global only)
}

// ---- FG: F_{dst} = F_{src} * M^p  /  G_{dst} = M^p * G_{src}; 1 matmul/block ----
__global__ __launch_bounds__(256) void k_fg(const float* __restrict__ MP,
                                            float* __restrict__ Fb,
                                            float* __restrict__ Gb,
                                            const int phase) {
  const int tid = threadIdx.x;
  const int nHalf = phase ? 12 : 3;
  const int half = blockIdx.x / nHalf, r = blockIdx.x % nHalf;
  int src, dst, msl;
  if (phase == 0) { src = 0; dst = r + 1; msl = (r == 0) ? 0 : (r == 1) ? 1 : 6; }
  else { const int b = r / 4 + 1, s = r % 4; src = s; dst = 4 * b + s;
         msl = (b == 1) ? 2 : (b == 2) ? 3 : 7; }
  const float* __restrict__ Mx = MP + msl * 4096;
  if (half == 0) {
    const int j = tid & 63, ih = tid >> 6;
    const float* Fs = Fb + src * 2048;
    float* Fd = Fb + dst * 2048;
#pragma unroll
    for (int u = 0; u < 8; ++u) {
      const int i = ih * 8 + u;
      float acc = 0.f;
#pragma unroll 8
      for (int q = 0; q < 64; ++q) acc = fmaf(Fs[i * 64 + q], Mx[q * 64 + j], acc);
      Fd[i * 64 + j] = acc;
    }
  } else {
    const int q = tid & 31, ih = tid >> 5;
    const float* Gs = Gb + src * 2048;
    float* Gd = Gb + dst * 2048;
#pragma unroll
    for (int u = 0; u < 8; ++u) {
      const int i = ih * 8 + u;
      float acc = 0.f;
#pragma unroll 8
      for (int p = 0; p < 64; ++p) acc = fmaf(Mx[i * 64 + p], Gs[p * 32 + q], acc);
      Gd[i * 32 + q] = acc;
    }
  }
}

// ---- KD: K_d = F_d * L (15 x 32x32) ----
__global__ __launch_bounds__(256) void k_kd(const float* __restrict__ Fb,
                                            const float* __restrict__ L,
                                            float* __restrict__ Kd) {
  const int o = blockIdx.x * 256 + threadIdx.x;   // < 15360
  const int d = o >> 10, i = (o >> 5) & 31, q = o & 31;
  float acc = 0.f;
#pragma unroll 8
  for (int j = 0; j < 64; ++j) acc = fmaf(Fb[d * 2048 + i * 64 + j], L[j * 32 + q], acc);
  Kd[o] = acc;
}

// ---- ASM: assemble BOh (tiled f16) and GCh (tiled f16) ----
__global__ __launch_bounds__(256) void k_asm(const float* __restrict__ Fb,
                                             const float* __restrict__ Gb,
                                             const float* __restrict__ Kd,
                                             f16* __restrict__ BOt,
                                             f16* __restrict__ GCt) {
  const int sid = blockIdx.x * 256 + threadIdx.x;
  if (sid < 512 * 72) {            // BOh: 32 mt x 18 ks x 4 lg x 16 l slots
    const int l = sid & 15, lg = (sid >> 4) & 3;
    const int t18 = sid >> 6;
    const int mt = t18 / 18, ks = t18 - mt * 18;
    const int i = mt, t = l;
    const int k0 = ks * 32 + lg * 8;
    f16x8 hv;
    if (k0 + 7 < 64) {
#pragma unroll
      for (int e = 0; e < 8; ++e) hv[e] = (f16)Fb[t * 2048 + i * 64 + k0 + e];
    } else {
      const int kk = k0 - 64;
      const int s = kk >> 5, q0 = kk & 31;
      if (s < t) {
        const int d = t - 1 - s;
#pragma unroll
        for (int e = 0; e < 8; ++e) hv[e] = (f16)Kd[d * 1024 + i * 32 + q0 + e];
      } else {
#pragma unroll
        for (int e = 0; e < 8; ++e) hv[e] = (f16)0.f;
      }
    }
    *reinterpret_cast<f16x8*>(BOt + (size_t)sid * 8) = hv;
  } else {                          // GCh: 4 jt x 16 ks x 4 lg x 16 l slots
    const int sid2 = sid - 512 * 72;
    if (sid2 < 4096) {
      const int l = sid2 & 15, lg = (sid2 >> 4) & 3;
      const int t16 = sid2 >> 6;
      const int jt = t16 >> 4, ks = t16 & 15;
      const int j = jt * 16 + l;
      const int ii = lg * 8;
      f16x8 hv;
#pragma unroll
      for (int e = 0; e < 8; ++e) hv[e] = (f16)Gb[(15 - ks) * 2048 + j * 32 + ii + e];
      *reinterpret_cast<f16x8*>(GCt + (size_t)sid2 * 8) = hv;
    }
  }
}

// ---- f16 MFMA GEMM on tiled operands. C[c][mm] = sum_k Zh[c][k]*B[mm][k].
//      MODE 0: B=GCh (KS_B=16, A ks 2..17), out VT[c][64]; extra block runs the
//              M32..M2048 squaring chain (MPow slot 4 -> slot 5).
//      MODE 1: B=BOh (KS_B=18, A ks 0..17), out d_out[i*NSTEP + c*16 + t] ----
template <int MODE>
__global__ __launch_bounds__(256) void k_mfma(const f16* __restrict__ At,
                                              const f16* __restrict__ Bt,
                                              float* __restrict__ outp,
                                              float* __restrict__ MPow) {
  if (MODE == 0 && blockIdx.x == CCH / 128) {
    __shared__ __align__(16) float C0[64 * 68], C1[64 * 68];
    const int tid2 = threadIdx.x;
    const float* M16 = MPow + 4 * 4096;
    for (int e = tid2; e < 4096; e += 256)
      C0[(e >> 6) * 68 + (e & 63)] = M16[e];
    __syncthreads();
    float* cur = C0;
    float* nxt = C1;
    for (int s = 0; s < 7; ++s) {           // M32, M64, ..., M2048
      if (tid2 < 128)
        mm128(cur, cur, nxt, (s == 6) ? (MPow + 5 * 4096) : nullptr, tid2);
      __syncthreads();
      float* t = cur; cur = nxt; nxt = t;
    }
    return;
  }
  constexpr int KSTEPS = MODE ? 18 : 16;
  constexpr int AKS0 = MODE ? 0 : 2;
  constexpr int KSB = MODE ? 18 : 16;
  const int tid = threadIdx.x;
  const int wave = tid >> 6, lane = tid & 63;
  const int l15 = lane & 15, lg = lane >> 4;
  const int nn0 = blockIdx.x * 128;
  const int ct0 = blockIdx.x * 8 + wave * 2;
  const int bt0 = MODE ? blockIdx.y * 4 : 0;
  const int laneoff = (lg * 16 + l15) * 8;
  f32x4 acc[2][4] = {};
#pragma unroll 2
  for (int su = 0; su < KSTEPS; ++su) {
    const f16x8 a0 = *reinterpret_cast<const f16x8*>(At + (size_t)((ct0 + 0) * 18 + AKS0 + su) * 512 + laneoff);
    const f16x8 a1 = *reinterpret_cast<const f16x8*>(At + (size_t)((ct0 + 1) * 18 + AKS0 + su) * 512 + laneoff);
#pragma unroll
    for (int bf = 0; bf < 4; ++bf) {
      const f16x8 b = *reinterpret_cast<const f16x8*>(Bt + (size_t)((bt0 + bf) * KSB + su) * 512 + laneoff);
      acc[0][bf] = __builtin_amdgcn_mfma_f32_16x16x32_f16(a0, b, acc[0][bf], 0, 0, 0);
      acc[1][bf] = __builtin_amdgcn_mfma_f32_16x16x32_f16(a1, b, acc[1][bf], 0, 0, 0);
    }
  }
  // D layout: col = lane&15 (mm), row = lg*4 + reg (c)  [m89-verified]
#pragma unroll
  for (int af = 0; af < 2; ++af)
#pragma unroll
    for (int bf = 0; bf < 4; ++bf)
#pragma unroll
      for (int rg = 0; rg < 4; ++rg) {
        const int c = nn0 + wave * 32 + af * 16 + lg * 4 + rg;
        const int mm = bt0 * 16 + bf * 16 + l15;
        if (MODE) {
          outp[(size_t)(mm >> 4) * NSTEP + (size_t)c * 16 + (mm & 15)] = acc[af][bf][rg];
        } else {
          outp[(size_t)c * 64 + mm] = acc[af][bf][rg];
        }
      }
}

// ---------------- scan matvec: row-in-registers + readlane broadcast ----------------
__device__ __forceinline__ float lane_bcast(float v, int l) {
  return __uint_as_float(__builtin_amdgcn_readlane(__float_as_uint(v), l));
}

// 4 accumulator chains; v is added at the END (ds_read gets a full step of slack).
__device__ __forceinline__ float matvec_dot(const float* __restrict__ Prow, float x) {
  float a0 = 0.f, a1 = 0.f, a2 = 0.f, a3 = 0.f;
#pragma unroll
  for (int j = 0; j < 16; ++j) {
    a0 = fmaf(Prow[j +  0], lane_bcast(x, j +  0), a0);
    a1 = fmaf(Prow[j + 16], lane_bcast(x, j + 16), a1);
    a2 = fmaf(Prow[j + 32], lane_bcast(x, j + 32), a2);
    a3 = fmaf(Prow[j + 48], lane_bcast(x, j + 48), a3);
  }
  return (a0 + a1) + (a2 + a3);
}

// stage `n` floats from g into lds (64 lanes, float4, 8 loads in flight)
__device__ __forceinline__ void stage_lds(const float* __restrict__ g,
                                          float* __restrict__ lds,
                                          int n, int lane) {
  const int iters = n >> 8;                  // 256 floats per iter
  for (int r = 0; r < iters; r += 8) {
    float4 tmp[8];
#pragma unroll
    for (int u = 0; u < 8; ++u)
      tmp[u] = *reinterpret_cast<const float4*>(g + (size_t)(r + u) * 256 + lane * 4);
#pragma unroll
    for (int u = 0; u < 8; ++u)
      *reinterpret_cast<float4*>(lds + (size_t)(r + u) * 256 + lane * 4) = tmp[u];
  }
}

__global__ __launch_bounds__(64, 1) void k_scanA(const float* __restrict__ MP,
                                                 const float* __restrict__ VT,
                                                 float* __restrict__ W) {
  __shared__ float SV[SB * 64];     // 32 KiB: this block's VT slice
  const int lane = threadIdx.x;
  const int b = blockIdx.x;
  stage_lds(VT + (size_t)b * SB * 64, SV, SB * 64, lane);
  const float* P = MP + 4 * 4096;   // M^16
  float Prow[64];
#pragma unroll
  for (int j = 0; j < 64; ++j) Prow[j] = P[lane * 64 + j];
  __syncthreads();
  float x = 0.f;
  for (int s = 0; s < SB; ++s) {
    const float v = SV[s * 64 + lane];
    x = matvec_dot(Prow, x) + v;
  }
  W[b * 64 + lane] = x;
}

__global__ __launch_bounds__(64, 1) void k_scanB(const float* __restrict__ MP,
                                                 const float* __restrict__ W,
                                                 float* __restrict__ XB) {
  __shared__ float SW[NBLK * 64];   // 32 KiB
  const int lane = threadIdx.x;
  stage_lds(W, SW, NBLK * 64, lane);
  const float* Q = MP + 5 * 4096;   // M^2048
  float Qrow[64];
#pragma unroll
  for (int j = 0; j < 64; ++j) Qrow[j] = Q[lane * 64 + j];
  __syncthreads();
  float x = 0.f;
  for (int b = 0; b < NBLK; ++b) {
    XB[b * 64 + lane] = x;          // state at start of scan-block b
    const float v = SW[b * 64 + lane];
    x = matvec_dot(Qrow, x) + v;
  }
}

__global__ __launch_bounds__(64, 1) void k_scanC(const float* __restrict__ MP,
                                                 const float* __restrict__ VT,
                                                 const float* __restrict__ XB,
                                                 f16* __restrict__ Zt) {
  __shared__ float SV[SB * 64];     // 32 KiB
  __shared__ float xt2[SB][68];     // 34 KiB  [s][j]
  const int lane = threadIdx.x;
  const int b = blockIdx.x;
  stage_lds(VT + (size_t)b * SB * 64, SV, SB * 64, lane);
  const float* P = MP + 4 * 4096;
  float Prow[64];
#pragma unroll
  for (int j = 0; j < 64; ++j) Prow[j] = P[lane * 64 + j];
  float x = XB[b * 64 + lane];
  __syncthreads();
  for (int s = 0; s < SB; ++s) {
    xt2[s][lane] = x;               // x_c BEFORE consuming v_c
    const float v = SV[s * 64 + lane];
    x = matvec_dot(Prow, x) + v;
  }
  __syncthreads();
  // write x-part (k=0..63 → ks 0..1) of tiled Zh
#pragma unroll
  for (int h = 0; h < 2; ++h) {
    const int s = h * 64 + lane;
    const int c = b * SB + s;
    const int ct = c >> 4, l = c & 15;
#pragma unroll
    for (int ks = 0; ks < 2; ++ks)
#pragma unroll
      for (int lg = 0; lg < 4; ++lg) {
        f16x8 hv;
#pragma unroll
        for (int e = 0; e < 8; ++e) hv[e] = (f16)xt2[s][ks * 32 + lg * 8 + e];
        *reinterpret_cast<f16x8*>(Zt + ((size_t)(ct * 18 + ks) * 64 + lg * 16 + l) * 8) = hv;
      }
  }
}

extern "C" void kernel_launch(void* const* d_in, const int* in_sizes, int n_in,
                              void* d_out, int out_size, void* d_ws, size_t ws_size,
                              hipStream_t stream) {
  const float* y = (const float*)d_in[0];
  const float* A = (const float*)d_in[1];
  const float* H = (const float*)d_in[2];
  const float* L = (const float*)d_in[3];
  float* ws = (float*)d_ws;
  f16* Zt   = reinterpret_cast<f16*>(ws + OFF_ZH);
  float* VT = ws + OFF_VT;
  float* MP = ws + OFF_MP;
  f16* BOt  = reinterpret_cast<f16*>(ws + OFF_BO);
  f16* GCt  = reinterpret_cast<f16*>(ws + OFF_GC);
  float* Fb = ws + OFF_FB;
  float* Gb = ws + OFF_GB;
  float* Kd = ws + OFF_KD;
  float* W  = ws + OFF_W;
  float* XB = ws + OFF_XB;
  float* out = (float*)d_out;

  k_pack<<<dim3(CCH / 16), dim3(256), 0, stream>>>(y, Zt);
  k_p1<<<dim3(1), dim3(128), 0, stream>>>(A, H, L, MP, Fb, Gb);
  k_fg<<<dim3(6), dim3(256), 0, stream>>>(MP, Fb, Gb, 0);
  k_fg<<<dim3(24), dim3(256), 0, stream>>>(MP, Fb, Gb, 1);
  k_kd<<<dim3(60), dim3(256), 0, stream>>>(Fb, L, Kd);
  k_asm<<<dim3(160), dim3(256), 0, stream>>>(Fb, Gb, Kd, BOt, GCt);
  // V GEMM (MFMA) + hidden M32..M2048 chain in the extra block
  k_mfma<0><<<dim3(CCH / 128 + 1, 1), dim3(256), 0, stream>>>(Zt, GCt, VT, MP);
  k_scanA<<<dim3(NBLK), dim3(64), 0, stream>>>(MP, VT, W);
  k_scanB<<<dim3(1), dim3(64), 0, stream>>>(MP, W, XB);
  k_scanC<<<dim3(NBLK), dim3(64), 0, stream>>>(MP, VT, XB, Zt);
  // Output GEMM (MFMA): out[i][c*16+t] = sum_k Zh[c][k] * BOh[i*16+t][k]
  k_mfma<1><<<dim3(CCH / 128, MOUT / 64), dim3(256), 0, stream>>>(Zt, BOt, out, nullptr);
}